// Round 1
// baseline (218.909 us; speedup 1.0000x reference)
//
#include <hip/hip_runtime.h>
#include <hip/hip_bf16.h>
#include <stdint.h>

// Sizes (fixed by the problem): B=8, n=64, C=32, O=32
#define B_   8
#define N_   64
#define C_   32
#define NC   2048      // N*C
#define NNC  131072    // N*N*C
#define N3C  8388608   // N*N*N*C  (per-batch x elements)
#define CMP  1048576   // per-component floats (B*N*N*C)

// ws layout (float offsets). comps 0..5: s1,s2,s3 (raw sums over the reduced
// axis), d12,d13,d23 (raw diagonal values).
#define A1OFF  6291456ull                 // 6*CMP : a1 [B][64][320]
#define A0OFF  6455296ull                 // a1 + 163840 : a0 [B][160]
#define U1POFF 6456576ull                 // u1p [B][64][32]  (a1@W12+b12 + a0@W02+b02 + b22)
#define U1TOFF 6472960ull                 // u1t [B][64][32]  (a1@W12t+b12t)
#define FOVOFF 6489344ull                 // fov [B][64][32]  (a1@W11+b11 + a0@W01+b01)

__device__ __forceinline__ unsigned short bf16b(float x){
    unsigned u = __float_as_uint(x);
    u += 0x7FFFu + ((u >> 16) & 1u);      // RNE
    return (unsigned short)(u >> 16);
}
__device__ __forceinline__ float lo16(unsigned u){ return __uint_as_float(u << 16); }
__device__ __forceinline__ float hi16(unsigned u){ return __uint_as_float(u & 0xFFFF0000u); }

// ---------------------------------------------------------------------------
// K1: s1[b,j,k,c] = sum_i x[b,i,j,k,c].  Block = (b, 1KB-chunk of jkc space).
__global__ __launch_bounds__(256) void k_s1(const float* __restrict__ x,
                                            float* __restrict__ s1){
    int blk = blockIdx.x;                 // 1024 blocks: b*128 + chunk
    int b = blk >> 7, chunk = blk & 127;
    size_t base = (size_t)b * N3C + (size_t)chunk * 1024 + threadIdx.x * 4;
    float4 acc = make_float4(0.f, 0.f, 0.f, 0.f);
    #pragma unroll 8
    for (int i = 0; i < 64; ++i){
        float4 v = *reinterpret_cast<const float4*>(x + base + (size_t)i * NNC);
        acc.x += v.x; acc.y += v.y; acc.z += v.z; acc.w += v.w;
    }
    *reinterpret_cast<float4*>(s1 + (size_t)b * NNC + chunk * 1024 + threadIdx.x * 4) = acc;
}

// ---------------------------------------------------------------------------
// K2: block = (b,i). s2[b,i,k,c] = sum_j; s3[b,i,j,c] = sum_k.
__global__ __launch_bounds__(256) void k_s2s3(const float* __restrict__ x,
                                              float* __restrict__ s2,
                                              float* __restrict__ s3){
    int blk = blockIdx.x;                 // 512 blocks: b*64 + i
    int b = blk >> 6, i = blk & 63;
    const float* base = x + (size_t)b * N3C + (size_t)i * NNC;
    int t  = threadIdx.x;
    int kg = t >> 3;                      // 0..31 (k and k+32)
    int c4 = (t & 7) * 4;
    float4 a0 = make_float4(0.f,0.f,0.f,0.f), a1 = a0;
    __shared__ float red[8][32][32];      // [jj][kg][c] partials (32KB)
    for (int j0 = 0; j0 < 64; j0 += 8){
        #pragma unroll
        for (int jj = 0; jj < 8; ++jj){
            const float* row = base + (size_t)(j0 + jj) * NC;
            float4 v0 = *reinterpret_cast<const float4*>(row + kg * 32 + c4);
            float4 v1 = *reinterpret_cast<const float4*>(row + (kg + 32) * 32 + c4);
            a0.x += v0.x; a0.y += v0.y; a0.z += v0.z; a0.w += v0.w;
            a1.x += v1.x; a1.y += v1.y; a1.z += v1.z; a1.w += v1.w;
            float4 s;
            s.x = v0.x + v1.x; s.y = v0.y + v1.y; s.z = v0.z + v1.z; s.w = v0.w + v1.w;
            *reinterpret_cast<float4*>(&red[jj][kg][c4]) = s;
        }
        __syncthreads();
        {
            int jj = t >> 5, c = t & 31;
            float s = 0.f;
            #pragma unroll
            for (int g = 0; g < 32; ++g) s += red[jj][g][c];
            s3[(size_t)b * NNC + (size_t)i * NC + (j0 + jj) * 32 + c] = s;
        }
        __syncthreads();
    }
    float* o = s2 + (size_t)b * NNC + (size_t)i * NC;
    *reinterpret_cast<float4*>(o + kg * 32 + c4)        = a0;
    *reinterpret_cast<float4*>(o + (kg + 32) * 32 + c4) = a1;
}

// ---------------------------------------------------------------------------
// K_diag: block=(b,p). d12[b,p,k,c]=x[b,p,p,k,c]; d13[b,p,q,c]=x[b,p,q,p,c];
// d23[b,p,q,c]=x[b,p,q,q,c].
__global__ __launch_bounds__(256) void k_diag(const float* __restrict__ x,
                                              float* __restrict__ d12,
                                              float* __restrict__ d13,
                                              float* __restrict__ d23){
    int blk = blockIdx.x;                 // 512: b*64 + p
    int b = blk >> 6, p = blk & 63;
    const float* bp = x + (size_t)b * N3C + (size_t)p * NNC;
    int t = threadIdx.x;
    #pragma unroll
    for (int r = 0; r < 2; ++r){
        int i4 = t + r * 256;
        float4 v = *reinterpret_cast<const float4*>(bp + (size_t)p * NC + i4 * 4);
        *reinterpret_cast<float4*>(d12 + (size_t)b * NNC + (size_t)p * NC + i4 * 4) = v;
    }
    #pragma unroll
    for (int r = 0; r < 8; ++r){
        int idx = t + r * 256;            // q*32 + c
        int q = idx >> 5, c = idx & 31;
        float v13 = bp[(size_t)q * NC + p * 32 + c];
        float v23 = bp[(size_t)q * NC + q * 32 + c];
        d13[(size_t)b * NNC + (size_t)p * NC + idx] = v13;
        d23[(size_t)b * NNC + (size_t)p * NC + idx] = v23;
    }
}

// ---------------------------------------------------------------------------
// K3: a1 [B][64][320] and a0 [B][160] from comps. Block = (b, m), m in 0..4
// over comps {s1, s2, d12, d13, d23}.
__global__ __launch_bounds__(256) void k_a1a0(const float* __restrict__ ws,
                                              float* __restrict__ a1,
                                              float* __restrict__ a0){
    int b = blockIdx.x / 5, m = blockIdx.x % 5;
    const int   comps[5] = {0, 1, 3, 4, 5};
    const int   rowch[5] = {1, 2, 4, 6, 8};
    const int   colch[5] = {0, -1, 3, 5, 7};
    const int   a0i  [5] = {0, -1, 1, 2, 3};
    const float rsc  [5] = {1.f/4096.f, 1.f/4096.f, 1.f/64.f, 1.f/64.f, 1.f/64.f};
    const float tsc  [5] = {1.f/262144.f, 0.f, 1.f/4096.f, 1.f/4096.f, 1.f/4096.f};

    const float* M = ws + (size_t)comps[m] * CMP + (size_t)b * NNC;
    int t = threadIdx.x, c = t & 31, qb = (t >> 5) * 8;
    float colacc[8] = {0.f,0.f,0.f,0.f,0.f,0.f,0.f,0.f};
    __shared__ float red[2048];
    __shared__ float rowc[64][32];
    for (int p0 = 0; p0 < 64; p0 += 8){
        #pragma unroll
        for (int pp = 0; pp < 8; ++pp){
            const float* row = M + (size_t)(p0 + pp) * NC;
            float part = 0.f;
            #pragma unroll
            for (int kk = 0; kk < 8; ++kk){
                float v = row[(qb + kk) * 32 + c];
                colacc[kk] += v; part += v;
            }
            red[pp * 256 + t] = part;
        }
        __syncthreads();
        {
            int pp = t >> 5, cc = t & 31;
            float s = 0.f;
            #pragma unroll
            for (int g = 0; g < 8; ++g) s += red[pp * 256 + g * 32 + cc];
            rowc[p0 + pp][cc] = s;
            a1[((size_t)b * 64 + p0 + pp) * 320 + rowch[m] * 32 + cc] = s * rsc[m];
        }
        __syncthreads();
    }
    if (colch[m] >= 0){
        #pragma unroll
        for (int kk = 0; kk < 8; ++kk)
            a1[((size_t)b * 64 + qb + kk) * 320 + colch[m] * 32 + c] = colacc[kk] * rsc[m];
    }
    if (a0i[m] >= 0){
        int pg = t >> 5;
        float tp = 0.f;
        #pragma unroll
        for (int r = 0; r < 8; ++r) tp += rowc[pg * 8 + r][c];
        red[t] = tp;
        __syncthreads();
        if (t < 32){
            float tot = 0.f;
            #pragma unroll
            for (int g = 0; g < 8; ++g) tot += red[g * 32 + t];
            a0[(size_t)b * 160 + a0i[m] * 32 + t] = tot * tsc[m];
        }
    }
    if (m == 2){                          // d12: triple diagonal -> chunk9 + a0[4]
        __syncthreads();
        float dp = 0.f;
        #pragma unroll
        for (int r = 0; r < 8; ++r){
            int p = (t >> 5) + 8 * r;
            float dv = M[(size_t)p * NC + p * 32 + c];
            a1[((size_t)b * 64 + p) * 320 + 9 * 32 + c] = dv;
            dp += dv;
        }
        red[t] = dp;
        __syncthreads();
        if (t < 32){
            float s = 0.f;
            #pragma unroll
            for (int g = 0; g < 8; ++g) s += red[g * 32 + t];
            a0[(size_t)b * 160 + 4 * 32 + t] = s * (1.f/64.f);
        }
    }
}

// ---------------------------------------------------------------------------
// K3b: u1p / u1t / fov vectors from a1,a0.
__global__ __launch_bounds__(256) void k_uvec(float* __restrict__ ws,
        const float* __restrict__ W12,  const float* __restrict__ b12,
        const float* __restrict__ W12t, const float* __restrict__ b12t,
        const float* __restrict__ W02,  const float* __restrict__ b02,
        const float* __restrict__ W11,  const float* __restrict__ b11,
        const float* __restrict__ W01,  const float* __restrict__ b01,
        const float* __restrict__ b22){
    int b = blockIdx.x >> 3, pg = blockIdx.x & 7;   // 64 blocks
    int t = threadIdx.x;
    int p = pg * 8 + (t >> 5), o = t & 31;
    const float* a1r = ws + A1OFF + ((size_t)b * 64 + p) * 320;
    const float* a0r = ws + A0OFF + (size_t)b * 160;
    float accP = b12[o] + b02[o] + b22[o];
    float accT = b12t[o];
    float accF = b11[o] + b01[o];
    for (int f = 0; f < 320; ++f){
        float a = a1r[f];
        accP = fmaf(a, W12 [f * 32 + o], accP);
        accT = fmaf(a, W12t[f * 32 + o], accT);
        accF = fmaf(a, W11 [f * 32 + o], accF);
    }
    for (int g = 0; g < 160; ++g){
        float a = a0r[g];
        accP = fmaf(a, W02[g * 32 + o], accP);
        accF = fmaf(a, W01[g * 32 + o], accF);
    }
    size_t idx = ((size_t)b * 64 + p) * 32 + o;
    ws[U1POFF + idx] = accP;
    ws[U1TOFF + idx] = accT;
    ws[FOVOFF + idx] = accF;
}

// ---------------------------------------------------------------------------
// K4: out[b,p,q,o] = sum_f A[q][f]*W22[f][o] + sum_f B[q][f]*W22[192+f][o]
//                    + u1p[b,p,o] + u1t[b,q,o] + (p==q)*fov[b,p,o]
// A[q][f] = scale_t * comp_t[b,p,q,c], B[q][f] = scale_t * comp_t[b,q,p,c].
// A,B,W staged in LDS as bf16 (fp32 accumulate). Block = (b,p).
__global__ __launch_bounds__(256) void k_out(const float* __restrict__ ws,
                                             const float* __restrict__ W22,
                                             float* __restrict__ out){
    __shared__ __align__(16) unsigned short Ast[192 * 68];  // [f][q] padded to 68
    __shared__ __align__(16) unsigned short Bst[192 * 68];
    __shared__ __align__(16) unsigned short Wls[192 * 32];  // [f][o]
    int blk = blockIdx.x;                 // 512: b*64 + p
    int b = blk >> 6, p = blk & 63;
    int t = threadIdx.x;

    // Stage A (rows comp[b,p,q,:]) and B (cols comp[b,q,p,:]) as bf16, scaled.
    for (int t6 = 0; t6 < 6; ++t6){
        float sc = (t6 < 3) ? (1.f/64.f) : 1.f;
        const float* cmp = ws + (size_t)t6 * CMP + (size_t)b * NNC;
        #pragma unroll
        for (int r = 0; r < 2; ++r){
            int i4 = t + r * 256;         // 0..511
            int q = i4 >> 3, c4 = (i4 & 7) * 4;
            int f = t6 * 32 + c4;
            float4 va = *reinterpret_cast<const float4*>(cmp + (size_t)p * NC + i4 * 4);
            Ast[(f+0)*68 + q] = bf16b(va.x * sc);
            Ast[(f+1)*68 + q] = bf16b(va.y * sc);
            Ast[(f+2)*68 + q] = bf16b(va.z * sc);
            Ast[(f+3)*68 + q] = bf16b(va.w * sc);
            float4 vb = *reinterpret_cast<const float4*>(cmp + (size_t)q * NC + p * 32 + c4);
            Bst[(f+0)*68 + q] = bf16b(vb.x * sc);
            Bst[(f+1)*68 + q] = bf16b(vb.y * sc);
            Bst[(f+2)*68 + q] = bf16b(vb.z * sc);
            Bst[(f+3)*68 + q] = bf16b(vb.w * sc);
        }
    }
    // Stage W half 0 (rows 0..191)
    #pragma unroll
    for (int r = 0; r < 6; ++r){
        int idx = t + r * 256;            // *4 floats, 0..6143
        int f = idx >> 3, o4 = (idx & 7) * 4;
        float4 w = *reinterpret_cast<const float4*>(W22 + (size_t)idx * 4);
        Wls[f*32 + o4 + 0] = bf16b(w.x);
        Wls[f*32 + o4 + 1] = bf16b(w.y);
        Wls[f*32 + o4 + 2] = bf16b(w.z);
        Wls[f*32 + o4 + 3] = bf16b(w.w);
    }
    __syncthreads();

    int qi = t & 15, oi = t >> 4;
    int q0 = qi * 4, o0 = oi * 2;
    float acc00=0,acc01=0,acc10=0,acc11=0,acc20=0,acc21=0,acc30=0,acc31=0;

    #pragma unroll 8
    for (int f = 0; f < 192; ++f){
        uint2 a4 = *reinterpret_cast<const uint2*>(Ast + f * 68 + q0);
        unsigned wp = *reinterpret_cast<const unsigned*>(Wls + f * 32 + o0);
        float w0v = lo16(wp), w1v = hi16(wp);
        float A0v = lo16(a4.x), A1v = hi16(a4.x), A2v = lo16(a4.y), A3v = hi16(a4.y);
        acc00 = fmaf(A0v, w0v, acc00); acc01 = fmaf(A0v, w1v, acc01);
        acc10 = fmaf(A1v, w0v, acc10); acc11 = fmaf(A1v, w1v, acc11);
        acc20 = fmaf(A2v, w0v, acc20); acc21 = fmaf(A2v, w1v, acc21);
        acc30 = fmaf(A3v, w0v, acc30); acc31 = fmaf(A3v, w1v, acc31);
    }
    __syncthreads();
    // Stage W half 1 (rows 192..383)
    #pragma unroll
    for (int r = 0; r < 6; ++r){
        int idx = t + r * 256;
        int f = idx >> 3, o4 = (idx & 7) * 4;
        float4 w = *reinterpret_cast<const float4*>(W22 + 6144 + (size_t)idx * 4);
        Wls[f*32 + o4 + 0] = bf16b(w.x);
        Wls[f*32 + o4 + 1] = bf16b(w.y);
        Wls[f*32 + o4 + 2] = bf16b(w.z);
        Wls[f*32 + o4 + 3] = bf16b(w.w);
    }
    __syncthreads();
    #pragma unroll 8
    for (int f = 0; f < 192; ++f){
        uint2 a4 = *reinterpret_cast<const uint2*>(Bst + f * 68 + q0);
        unsigned wp = *reinterpret_cast<const unsigned*>(Wls + f * 32 + o0);
        float w0v = lo16(wp), w1v = hi16(wp);
        float A0v = lo16(a4.x), A1v = hi16(a4.x), A2v = lo16(a4.y), A3v = hi16(a4.y);
        acc00 = fmaf(A0v, w0v, acc00); acc01 = fmaf(A0v, w1v, acc01);
        acc10 = fmaf(A1v, w0v, acc10); acc11 = fmaf(A1v, w1v, acc11);
        acc20 = fmaf(A2v, w0v, acc20); acc21 = fmaf(A2v, w1v, acc21);
        acc30 = fmaf(A3v, w0v, acc30); acc31 = fmaf(A3v, w1v, acc31);
    }

    // Epilogue: bias/row/col/diag terms and store.
    size_t ub = U1POFF + ((size_t)b * 64 + p) * 32;
    float up0 = ws[ub + o0], up1 = ws[ub + o0 + 1];
    const float* fovp = ws + FOVOFF + ((size_t)b * 64 + p) * 32;
    float accs[4][2] = {{acc00,acc01},{acc10,acc11},{acc20,acc21},{acc30,acc31}};
    #pragma unroll
    for (int iq = 0; iq < 4; ++iq){
        int q = q0 + iq;
        size_t tb = U1TOFF + ((size_t)b * 64 + q) * 32;
        float e0 = up0 + ws[tb + o0];
        float e1 = up1 + ws[tb + o0 + 1];
        if (q == p){ e0 += fovp[o0]; e1 += fovp[o0 + 1]; }
        float2 v; v.x = accs[iq][0] + e0; v.y = accs[iq][1] + e1;
        *reinterpret_cast<float2*>(out + (((size_t)b * 64 + p) * 64 + q) * 32 + o0) = v;
    }
}

// ---------------------------------------------------------------------------
extern "C" void kernel_launch(void* const* d_in, const int* in_sizes, int n_in,
                              void* d_out, int out_size, void* d_ws, size_t ws_size,
                              hipStream_t stream){
    const float* x    = (const float*)d_in[0];
    const float* W22  = (const float*)d_in[1];
    const float* b22  = (const float*)d_in[2];
    const float* W12  = (const float*)d_in[3];
    const float* b12  = (const float*)d_in[4];
    const float* W12t = (const float*)d_in[5];
    const float* b12t = (const float*)d_in[6];
    const float* W02  = (const float*)d_in[7];
    const float* b02  = (const float*)d_in[8];
    const float* W11  = (const float*)d_in[9];
    const float* b11  = (const float*)d_in[10];
    const float* W01  = (const float*)d_in[11];
    const float* b01  = (const float*)d_in[12];
    float* out = (float*)d_out;
    float* ws  = (float*)d_ws;

    k_s1  <<<1024, 256, 0, stream>>>(x, ws);
    k_s2s3<<<512,  256, 0, stream>>>(x, ws + (size_t)CMP, ws + 2*(size_t)CMP);
    k_diag<<<512,  256, 0, stream>>>(x, ws + 3*(size_t)CMP, ws + 4*(size_t)CMP, ws + 5*(size_t)CMP);
    k_a1a0<<<40,   256, 0, stream>>>(ws, ws + A1OFF, ws + A0OFF);
    k_uvec<<<64,   256, 0, stream>>>(ws, W12, b12, W12t, b12t, W02, b02, W11, b11, W01, b01, b22);
    k_out <<<512,  256, 0, stream>>>(ws, W22, out);
}